// Round 5
// baseline (192.546 us; speedup 1.0000x reference)
//
#include <hip/hip_runtime.h>

#define NN 20000
#define NE 320000
#define FD 128
#define KTOT 640   // 4*128 (relations) + 128 (root/self)
#define BM 32      // rows per GEMM block

typedef float f32x4 __attribute__((ext_vector_type(4)));
typedef __bf16 bf16x8 __attribute__((ext_vector_type(8)));

__device__ __forceinline__ unsigned f2ord(float f) {
  unsigned u = __float_as_uint(f);
  return (u & 0x80000000u) ? ~u : (u | 0x80000000u);
}
__device__ __forceinline__ float ord2f(unsigned u) {
  return (u & 0x80000000u) ? __uint_as_float(u & 0x7FFFFFFFu) : __uint_as_float(~u);
}
__device__ __forceinline__ unsigned pkbf(float a, float b) {
  union { __bf16 h[2]; unsigned u; } p;
  p.h[0] = (__bf16)a; p.h[1] = (__bf16)b; return p.u;
}

// one prep kernel: mm seed, deg zero, x->bf16 pack, both layers' wt (B^T) build
__global__ void prep_kernel(unsigned* mm, int* deg,
                            const float* __restrict__ x, unsigned* __restrict__ xb,
                            const float* __restrict__ W1, const float* __restrict__ r1,
                            const float* __restrict__ W2, const float* __restrict__ r2,
                            __bf16* __restrict__ wt1, __bf16* __restrict__ wt2) {
  int i = blockIdx.x * blockDim.x + threadIdx.x;
  if (i == 0) { mm[0] = 0xFFFFFFFFu; mm[1] = 0u; }
  if (i < NN) deg[i] = 0;
  if (i < 2 * FD * KTOT) {
    int which = i / (FD * KTOT);
    int rem = i % (FD * KTOT);
    int n = rem / KTOT, k = rem % KTOT;
    const float* W = which ? W2 : W1;
    const float* rt = which ? r2 : r1;
    float v = (k < 512) ? W[(size_t)k * FD + n] : rt[(size_t)(k - 512) * FD + n];
    (which ? wt2 : wt1)[rem] = (__bf16)v;
  }
  if (i < NN * FD / 4) {
    float4 v = *(const float4*)(x + (size_t)i * 4);
    uint2 p;
    p.x = pkbf(v.x, v.y);
    p.y = pkbf(v.z, v.w);
    *(uint2*)(xb + (size_t)i * 2) = p;
  }
}

__global__ void histmm_kernel(const int* __restrict__ dst, const float* __restrict__ ew,
                              int* deg, unsigned* mm) {
  __shared__ unsigned smn[256], smx[256];
  unsigned lmn = 0xFFFFFFFFu, lmx = 0u;
  for (int i = blockIdx.x * blockDim.x + threadIdx.x; i < NE; i += gridDim.x * blockDim.x) {
    atomicAdd(&deg[dst[i]], 1);
    unsigned o = f2ord(ew[i]);
    lmn = (o < lmn) ? o : lmn;
    lmx = (o > lmx) ? o : lmx;
  }
  smn[threadIdx.x] = lmn; smx[threadIdx.x] = lmx;
  __syncthreads();
  for (int s = 128; s > 0; s >>= 1) {
    if (threadIdx.x < s) {
      unsigned a = smn[threadIdx.x], b = smn[threadIdx.x + s];
      smn[threadIdx.x] = (b < a) ? b : a;
      unsigned c = smx[threadIdx.x], d = smx[threadIdx.x + s];
      smx[threadIdx.x] = (d > c) ? d : c;
    }
    __syncthreads();
  }
  if (threadIdx.x == 0) { atomicMin(&mm[0], smn[0]); atomicMax(&mm[1], smx[0]); }
}

__global__ void scan_kernel(const int* __restrict__ deg, int* offs, int* cursor) {
  __shared__ int part[1024];
  const int CH = (NN + 1023) / 1024;  // 20
  int t = threadIdx.x;
  int b = t * CH;
  int e = (b + CH < NN) ? (b + CH) : NN;
  int s = 0;
  for (int i = b; i < e; ++i) s += deg[i];
  part[t] = s;
  __syncthreads();
  for (int off = 1; off < 1024; off <<= 1) {
    int v = part[t];
    int add = (t >= off) ? part[t - off] : 0;
    __syncthreads();
    part[t] = v + add;
    __syncthreads();
  }
  int excl = (t == 0) ? 0 : part[t - 1];
  for (int i = b; i < e; ++i) { offs[i] = excl; cursor[i] = excl; excl += deg[i]; }
  if (t == 1023) offs[NN] = part[1023];
}

__global__ void fill_kernel(const int* __restrict__ src, const int* __restrict__ dst,
                            const int* __restrict__ et, const float* __restrict__ ew,
                            const unsigned* __restrict__ mm, int* cursor,
                            int2* __restrict__ ed) {
  int e = blockIdx.x * blockDim.x + threadIdx.x;
  if (e >= NE) return;
  float mn = ord2f(mm[0]), mx = ord2f(mm[1]);
  float inv = 1.0f / (mx - mn + 1e-8f);
  int d = dst[e];
  int pos = atomicAdd(&cursor[d], 1);
  ed[pos] = make_int2(src[e] | (et[e] << 28), __float_as_int((ew[e] - mn) * inv));
}

// ---------------------------------------------------------------------------
// Aggregation: one wave per node, HALF-WAVE EDGE PAIRING.
// lanes 0-31 process even edge of each pair, lanes 32-63 the odd edge.
// Each lane gathers uint2 (4 bf16 feats): feats 4l..4l+3 of its half's edge.
// Main loop: 2 pairs (4 edges) in flight + next-group edge-record prefetch.
// End: __shfl_xor(32) cross-half sum, then write g[node][640] (4 rel + self).
// ---------------------------------------------------------------------------
__global__ __launch_bounds__(256) void aggregate_kernel(
    const unsigned* __restrict__ xb,   // [NN][64] packed bf16 pairs
    const int* __restrict__ offs, const int2* __restrict__ ed,
    unsigned* __restrict__ g) {        // [NN][320] u32
  int node = (int)((blockIdx.x * blockDim.x + threadIdx.x) >> 6);
  int lane = threadIdx.x & 63;
  if (node >= NN) return;
  int half = lane >> 5, l = lane & 31;
  int beg = offs[node], end = offs[node + 1];
  f32x4 a0 = {0.f, 0.f, 0.f, 0.f}, a1 = a0, a2 = a0, a3 = a0;

#define GAT(E, U)                                                        \
  do {                                                                   \
    int s_ = (E).x & 0x0FFFFFFF;                                         \
    U = *(const uint2*)(xb + (size_t)s_ * 64 + l * 2);                   \
  } while (0)
#define ACCW(E, U, WV)                                                   \
  do {                                                                   \
    float p0 = __uint_as_float((U).x << 16);                             \
    float p1 = __uint_as_float((U).x & 0xFFFF0000u);                     \
    float p2 = __uint_as_float((U).y << 16);                             \
    float p3 = __uint_as_float((U).y & 0xFFFF0000u);                     \
    unsigned r_ = ((unsigned)(E).x) >> 28;                               \
    float w0 = (r_ == 0) ? (WV) : 0.f, w1 = (r_ == 1) ? (WV) : 0.f;      \
    float w2 = (r_ == 2) ? (WV) : 0.f, w3 = (r_ == 3) ? (WV) : 0.f;      \
    a0[0] += w0 * p0; a0[1] += w0 * p1; a0[2] += w0 * p2; a0[3] += w0 * p3; \
    a1[0] += w1 * p0; a1[1] += w1 * p1; a1[2] += w1 * p2; a1[3] += w1 * p3; \
    a2[0] += w2 * p0; a2[1] += w2 * p1; a2[2] += w2 * p2; a2[3] += w2 * p3; \
    a3[0] += w3 * p0; a3[1] += w3 * p1; a3[2] += w3 * p2; a3[3] += w3 * p3; \
  } while (0)

  int j2 = beg;
  if (j2 + 4 <= end) {
    int2 eA = ed[j2 + half];
    int2 eB = ed[j2 + 2 + half];
    do {
      uint2 uA, uB;
      GAT(eA, uA);
      GAT(eB, uB);
      int2 eA2 = ed[j2 + 4 + half];   // prefetch (ed padded +8)
      int2 eB2 = ed[j2 + 6 + half];
      ACCW(eA, uA, __int_as_float(eA.y));
      ACCW(eB, uB, __int_as_float(eB.y));
      eA = eA2; eB = eB2;
      j2 += 4;
    } while (j2 + 4 <= end);
  }
  for (; j2 < end; j2 += 2) {          // masked tail pairs
    int je = j2 + half;
    int2 e = ed[(je < end) ? je : (end - 1)];
    float wv = (je < end) ? __int_as_float(e.y) : 0.f;
    uint2 u;
    GAT(e, u);
    ACCW(e, u, wv);
  }
#undef GAT
#undef ACCW

  // cross-half reduction: both halves end with the full per-node sums
#pragma unroll
  for (int q = 0; q < 4; ++q) {
    a0[q] += __shfl_xor(a0[q], 32, 64);
    a1[q] += __shfl_xor(a1[q], 32, 64);
    a2[q] += __shfl_xor(a2[q], 32, 64);
    a3[q] += __shfl_xor(a3[q], 32, 64);
  }

  unsigned* row = g + (size_t)node * 320;
  f32x4 va = half ? a2 : a0;           // half 0 writes rel 0,1; half 1 rel 2,3
  f32x4 vb = half ? a3 : a1;
  int r01 = half * 2;
  uint2 w0 = make_uint2(pkbf(va[0], va[1]), pkbf(va[2], va[3]));
  *(uint2*)(row + r01 * 64 + l * 2) = w0;
  uint2 w1 = make_uint2(pkbf(vb[0], vb[1]), pkbf(vb[2], vb[3]));
  *(uint2*)(row + (r01 + 1) * 64 + l * 2) = w1;
  row[256 + lane] = xb[(size_t)node * 64 + lane];  // root/self
}

// ---------------------------------------------------------------------------
// GEMM: out[m][n] = A[m][:] @ wt[n][:] + bias[n].  A = g rows (bf16, [m][640]).
// BM=32 rows/block, 512 thr (8 waves): wr=wave>>2 rows, wc=wave&3 cols 32 each.
// Whole-row A in XOR-swizzled LDS (byte ^ (row&7)<<4); B per-wave from global
// (L2-resident wt) into registers; ZERO barriers in the K-loop.
// ---------------------------------------------------------------------------
template <int BF16OUT>
__global__ __launch_bounds__(512, 2) void gemm_kernel(
    const unsigned* __restrict__ gA,   // [NN][320] u32
    const __bf16* __restrict__ wt, const float* __restrict__ bias,
    float* __restrict__ outf, __bf16* __restrict__ outb) {
  __shared__ unsigned As32[BM * 320];  // 40 KB
  int tid = threadIdx.x;
  int wave = tid >> 6, lane = tid & 63;
  int wr = wave >> 2, wc = wave & 3;
  int m0 = blockIdx.x * BM;
  int rl = wr * 16 + (lane & 15);
  int kfe = (lane >> 4) * 8;
  int c0 = wc * 32 + (lane & 15);
  const f32x4 zz = {0.f, 0.f, 0.f, 0.f};

  // ---- layout probe (R4-verified): decode acc slot -> (row,col) ----
  unsigned rowpack = 0, colpack0 = 0, colpack1 = 0;
  {
    if (tid < 256) {
      int row = tid >> 3;
      int wl = (tid & 7) * 2;
      unsigned val = pkbf((float)row * 0.03125f, (float)row * 0.03125f);
      int sw2 = (row & 7) << 2;
      As32[row * 320 + (wl ^ sw2)] = val;
      As32[row * 320 + ((wl + 1) ^ sw2)] = val;
    }
    __syncthreads();
    const char* Arow = (const char*)As32 + rl * 1280;
    int swb = (rl & 7) << 4;
    bf16x8 pa = *(const bf16x8*)(Arow + ((kfe * 2) ^ swb));
    bf16x8 ones, bp0, bp1;
#pragma unroll
    for (int i = 0; i < 8; ++i) ones[i] = (__bf16)1.0f;
    __bf16 c0v = (__bf16)((float)c0 * 0.0078125f);
    __bf16 c1v = (__bf16)((float)(c0 + 16) * 0.0078125f);
#pragma unroll
    for (int i = 0; i < 8; ++i) { bp0[i] = c0v; bp1[i] = c1v; }
    f32x4 P1 = __builtin_amdgcn_mfma_f32_16x16x32_bf16(pa, ones, zz, 0, 0, 0);
    f32x4 P2a = __builtin_amdgcn_mfma_f32_16x16x32_bf16(ones, bp0, zz, 0, 0, 0);
    f32x4 P2b = __builtin_amdgcn_mfma_f32_16x16x32_bf16(ones, bp1, zz, 0, 0, 0);
#pragma unroll
    for (int j = 0; j < 4; ++j) {
      rowpack |= ((unsigned)(int)(P1[j] + 0.5f)) << (8 * j);
      colpack0 |= ((unsigned)(int)(P2a[j] * 4.0f + 0.5f)) << (8 * j);
      colpack1 |= ((unsigned)(int)(P2b[j] * 4.0f + 0.5f)) << (8 * j);
    }
    __syncthreads();
  }

  // ---- load A tile [32][640] bf16 from g, swizzled (16B chunks) ----
  {
    int row = tid >> 4;       // 32 rows, 16 threads each
    int c16 = tid & 15;
    const uint4* srcp = (const uint4*)(gA + (size_t)(m0 + row) * 320);
    unsigned sw2 = (row & 7) << 2;
    unsigned* dstw = As32 + row * 320;
#pragma unroll
    for (int jj = 0; jj < 5; ++jj) {
      int chunk = c16 + 16 * jj;        // 80 chunks of 16B per row
      uint4 v = srcp[chunk];
      *(uint4*)(dstw + ((chunk * 4) ^ sw2)) = v;
    }
  }
  __syncthreads();

  // ---- K-loop: zero barriers ----
  f32x4 acc0 = zz, acc1 = zz;
  const __bf16* w0p = wt + (size_t)c0 * KTOT + kfe;
  const __bf16* w1p = w0p + 16 * KTOT;
  const char* Arow = (const char*)As32 + rl * 1280;
  int swb = (rl & 7) << 4;
#pragma unroll
  for (int step = 0; step < 20; ++step) {
    int b = (step * 64 + kfe * 2) ^ swb;
    bf16x8 a = *(const bf16x8*)(Arow + b);
    bf16x8 b0 = *(const bf16x8*)(w0p + step * 32);
    bf16x8 b1 = *(const bf16x8*)(w1p + step * 32);
    acc0 = __builtin_amdgcn_mfma_f32_16x16x32_bf16(a, b0, acc0, 0, 0, 0);
    acc1 = __builtin_amdgcn_mfma_f32_16x16x32_bf16(a, b1, acc1, 0, 0, 0);
  }

  // ---- epilogue (R4-verified) ----
#pragma unroll
  for (int j = 0; j < 4; ++j) {
    int rloc = (int)((rowpack >> (8 * j)) & 255u);
    size_t m = (size_t)(m0 + rloc);
    {
      int col = (int)((colpack0 >> (8 * j)) & 255u);
      float v = acc0[j] + bias[col];
      if (BF16OUT) outb[m * FD + col] = (__bf16)fmaxf(v, 0.f);
      else outf[m * FD + col] = v;
    }
    {
      int col = (int)((colpack1 >> (8 * j)) & 255u);
      float v = acc1[j] + bias[col];
      if (BF16OUT) outb[m * FD + col] = (__bf16)fmaxf(v, 0.f);
      else outf[m * FD + col] = v;
    }
  }
}

extern "C" void kernel_launch(void* const* d_in, const int* in_sizes, int n_in,
                              void* d_out, int out_size, void* d_ws, size_t ws_size,
                              hipStream_t stream) {
  const float* x  = (const float*)d_in[0];
  const int*   ei = (const int*)d_in[1];
  const int*   et = (const int*)d_in[2];
  const float* ew = (const float*)d_in[3];
  const float* W1 = (const float*)d_in[4];
  const float* r1 = (const float*)d_in[5];
  const float* b1 = (const float*)d_in[6];
  const float* W2 = (const float*)d_in[7];
  const float* r2 = (const float*)d_in[8];
  const float* b2 = (const float*)d_in[9];
  float* out = (float*)d_out;
  const int* src = ei;
  const int* dst = ei + NE;

  char* w = (char*)d_ws;
  size_t o = 0;
  auto take = [&](size_t bytes) -> char* {
    char* p = w + o;
    o += (bytes + 255) & ~(size_t)255;
    return p;
  };
  unsigned* mm  = (unsigned*)take(8);
  int* deg      = (int*)take((size_t)NN * 4);
  int* offs     = (int*)take((size_t)(NN + 1) * 4);
  int* cursor   = (int*)take((size_t)NN * 4);
  int2* ed      = (int2*)take((size_t)(NE + 8) * 8);  // +8 pad for prefetch
  unsigned* xb  = (unsigned*)take((size_t)NN * 64 * 4);
  unsigned* g   = (unsigned*)take((size_t)NN * 320 * 4);
  __bf16* h1    = (__bf16*)take((size_t)NN * FD * 2);
  __bf16* wt1   = (__bf16*)take((size_t)FD * KTOT * 2);
  __bf16* wt2   = (__bf16*)take((size_t)FD * KTOT * 2);
  (void)ws_size; (void)n_in; (void)in_sizes; (void)out_size;

  hipLaunchKernelGGL(prep_kernel, dim3((NN * FD / 4 + 255) / 256), dim3(256), 0, stream,
                     mm, deg, x, xb, W1, r1, W2, r2, wt1, wt2);
  hipLaunchKernelGGL(histmm_kernel, dim3(512), dim3(256), 0, stream, dst, ew, deg, mm);
  hipLaunchKernelGGL(scan_kernel, dim3(1), dim3(1024), 0, stream, deg, offs, cursor);
  hipLaunchKernelGGL(fill_kernel, dim3((NE + 255) / 256), dim3(256), 0, stream,
                     src, dst, et, ew, mm, cursor, ed);
  // layer 1
  hipLaunchKernelGGL(aggregate_kernel, dim3(NN / 4), dim3(256), 0, stream, xb, offs, ed, g);
  hipLaunchKernelGGL((gemm_kernel<1>), dim3(NN / BM), dim3(512), 0, stream,
                     g, wt1, b1, (float*)nullptr, h1);
  // layer 2
  hipLaunchKernelGGL(aggregate_kernel, dim3(NN / 4), dim3(256), 0, stream,
                     (const unsigned*)h1, offs, ed, g);
  hipLaunchKernelGGL((gemm_kernel<0>), dim3(NN / BM), dim3(512), 0, stream,
                     g, wt2, b2, out, (__bf16*)nullptr);
}